// Round 4
// baseline (320.131 us; speedup 1.0000x reference)
//
#include <hip/hip_runtime.h>

// Chunked linear attention (causal, unnormalized), bf16 MFMA, fp32 I/O.
// R7: R6 pipeline with the tb=0 GEMM1 fix (both dk halves of QK^T).
//   phA: split-scan, grid bh x slice x seg (64*8*2=1024), CPS=8, NSEG=2.
//   phB: block=(bh,n,tb). Unified stage order K0,K1,[H0,H1],P,V0,[V1]
//        with Bb[2] ping-pong; global->reg issue at stage i-1, reg->LDS
//        at stage i, consume at stage i+1. One barrier per stage.
// B=4 S=2048 H=16 D=128. ws: 64*16*128*128 bf16 = 32 MiB.

#define Bc 4
#define Sq 2048
#define Hh 16
#define Dd 128
#define RS (Hh * Dd)      // 2048
#define Cc 128
#define NCH (Sq / Cc)     // 16
#define BHt (Bc * Hh)     // 64
#define NSEG 2
#define CPS (NCH / NSEG)  // 8
#define SCALE 0.08838834764831845f

using frag_ab = __attribute__((ext_vector_type(8))) short;  // 8 bf16
using frag_cd = __attribute__((ext_vector_type(4))) float;  // 4 fp32

__device__ __forceinline__ unsigned short f2bf(float f) {
  union { float f; unsigned u; } x; x.f = f;
  unsigned r = x.u + 0x7FFFu + ((x.u >> 16) & 1u);  // RNE
  return (unsigned short)(r >> 16);
}
__device__ __forceinline__ float bf2f(unsigned short u) {
  union { unsigned u; float f; } x; x.u = ((unsigned)u) << 16;
  return x.f;
}
// swizzles: permute 8-element (16 B) blocks within a row -> frag b128 reads
// stay contiguous; writes spread across banks.
__device__ __forceinline__ int sw64(int r, int c) {
  return r * 64 + ((((c >> 3) ^ (r & 7)) << 3) | (c & 7));
}
__device__ __forceinline__ int sw128(int r, int c) {
  return r * 128 + ((((c >> 3) ^ (r & 15)) << 3) | (c & 7));
}
__device__ __forceinline__ int swKT(int dk, int t) {  // [dk 128][t 128]
  return dk * 128 + ((((t >> 3) ^ (dk ^ (dk >> 4))) & 15) << 3) + (t & 7);
}
__device__ __forceinline__ int swVT(int dv, int t) {  // [dv 16][t 128]
  return dv * 128 + ((((t >> 3) ^ dv) & 15) << 3) + (t & 7);
}

// ---------- phA: split scan. Block = (bh, slice, seg); scans CPS chunks ----
// bid layout: bh low 6 bits (XCD-colocate), slice bits 6-8, seg bit 9.
__global__ __launch_bounds__(256) void phA_state(const float* __restrict__ kg,
                                                 const float* __restrict__ vg,
                                                 unsigned short* __restrict__ st) {
  __shared__ unsigned short KT[128 * 128];  // 32 KB [dk][t]
  __shared__ unsigned short VT[16 * 128];   //  4 KB [dv][t]
  const int tid = threadIdx.x;
  const int bh = blockIdx.x & 63;
  const int slice = (blockIdx.x >> 6) & 7;
  const int seg = blockIdx.x >> 9;
  const int b = bh >> 4, h = bh & 15;
  const int dv0 = slice * 16;
  const size_t base = (size_t)b * Sq * RS + (size_t)h * Dd;
  const int w = tid >> 6, L = tid & 63, li = L & 15, q4 = L >> 4;
  const int kdk0 = (tid & 31) * 4;
  const int ktg4 = (tid >> 5) * 4;
  const int vdv0l = (tid & 3) * 4;
  const int vt0 = (tid >> 2) * 2;

  float4 rk[4][4];
  float4 rv[2];
  auto prefetch = [&](int n) {
    const size_t t0g = (size_t)n * Cc;
#pragma unroll
    for (int p = 0; p < 4; ++p) {
      const int t0 = p * 32 + ktg4;
#pragma unroll
      for (int i = 0; i < 4; ++i)
        rk[p][i] = *(const float4*)(kg + base + (t0g + t0 + i) * (size_t)RS + kdk0);
    }
#pragma unroll
    for (int i = 0; i < 2; ++i)
      rv[i] = *(const float4*)(vg + base + (t0g + vt0 + i) * (size_t)RS + dv0 + vdv0l);
  };

  frag_cd acc[2];
  acc[0] = (frag_cd){0.f, 0.f, 0.f, 0.f};
  acc[1] = (frag_cd){0.f, 0.f, 0.f, 0.f};
  const int n0 = seg * CPS;
  prefetch(n0);
  const size_t sbb = (size_t)bh * NCH * (128 * 128);

  auto store_acc = [&](int slot) {
    const size_t sb = sbb + (size_t)slot * (128 * 128);
#pragma unroll
    for (int nt = 0; nt < 2; ++nt)
#pragma unroll
      for (int r = 0; r < 4; ++r) {
        const int dv = dv0 + 4 * q4 + r;
        const int dk = 32 * w + 16 * nt + li;
        st[sb + (size_t)dv * 128 + dk] = f2bf(acc[nt][r]);
      }
  };

  for (int j = 0; j < CPS; ++j) {
    __syncthreads();  // prev chunk's frag reads done
#pragma unroll
    for (int p = 0; p < 4; ++p) {
      const int t0 = p * 32 + ktg4;
#pragma unroll
      for (int jj = 0; jj < 4; ++jj) {
        ushort4 u;
        u.x = f2bf(((const float*)&rk[p][0])[jj]);
        u.y = f2bf(((const float*)&rk[p][1])[jj]);
        u.z = f2bf(((const float*)&rk[p][2])[jj]);
        u.w = f2bf(((const float*)&rk[p][3])[jj]);
        *(ushort4*)&KT[swKT(kdk0 + jj, t0)] = u;
      }
    }
#pragma unroll
    for (int jj = 0; jj < 4; ++jj) {
      ushort2 u;
      u.x = f2bf(((const float*)&rv[0])[jj]);
      u.y = f2bf(((const float*)&rv[1])[jj]);
      *(ushort2*)&VT[swVT(vdv0l + jj, vt0)] = u;
    }
    if (j + 1 < CPS) prefetch(n0 + j + 1);  // HBM latency hides under LDS+MFMA
    __syncthreads();
    if (j > 0) store_acc(n0 + j);  // local EXCLUSIVE prefix
#pragma unroll
    for (int kt = 0; kt < 4; ++kt) {
      frag_ab af = *(const frag_ab*)&VT[swVT(li, 32 * kt + 8 * q4)];
#pragma unroll
      for (int nt = 0; nt < 2; ++nt) {
        frag_ab bf = *(const frag_ab*)&KT[swKT(32 * w + 16 * nt + li, 32 * kt + 8 * q4)];
        acc[nt] = __builtin_amdgcn_mfma_f32_16x16x32_bf16(af, bf, acc[nt], 0, 0, 0);
      }
    }
  }
  if (seg + 1 < NSEG) store_acc(n0);  // segment total T_0 -> slot 0
}

// ---------- phB: O = Qs*H_n + tril(Qs*K^T)*V, 64 query rows per block ----
// H_n = T_0 (slot 0, if n>=8) + local (slot n, if n&7). Pipelined stages.
__global__ __launch_bounds__(256, 3) void phB_out(const float* __restrict__ qg,
                                                  const float* __restrict__ kg,
                                                  const float* __restrict__ vg,
                                                  const unsigned short* __restrict__ st,
                                                  float* __restrict__ o) {
  __shared__ unsigned short QP[64 * 128];     // 16 KB: Qs rows of this tb, later P
  __shared__ unsigned short Bb[2][128 * 64];  // 2 x 16 KB ping-pong stages
  const int tid = threadIdx.x;
  const int bid = blockIdx.x;
  const int bh = bid & 63, n = (bid >> 6) & 15, tb = bid >> 10;
  const int b = bh >> 4, h = bh & 15;
  const size_t cbase = (size_t)b * Sq * RS + (size_t)n * Cc * RS + (size_t)h * Dd;
  const size_t tbase = cbase + (size_t)(64 * tb) * RS;
  const size_t sbh = (size_t)bh * NCH * (128 * 128);
  const int sseg = n >> 3, jj = n & 7;
  const int nmat = sseg + (jj ? 1 : 0);  // 0..2
  const int w = tid >> 6, L = tid & 63;
  const int wr = w >> 1, wc = w & 1, li = L & 15, q4 = L >> 4;

  frag_cd accO[2][4], accP[2][4];
#pragma unroll
  for (int i = 0; i < 2; ++i)
#pragma unroll
    for (int j = 0; j < 4; ++j) {
      accO[i][j] = (frag_cd){0.f, 0.f, 0.f, 0.f};
      accP[i][j] = (frag_cd){0.f, 0.f, 0.f, 0.f};
    }

  float4 sA[8], sB[8];       // K/V staging regs
  uint4 hA[2][4], hB[2][4];  // H carry staging regs (nmat<=2)

  // ---- staging lambdas (load = issue global->reg; write = reg->LDS) ----
  auto loadK = [&](int half, float4 (&s)[8]) {
#pragma unroll
    for (int it = 0; it < 8; ++it) {
      const int f = it * 256 + tid;
      const int t = f >> 4;
      const int c0 = (f & 15) << 2;
      s[it] = *(const float4*)(kg + cbase + (size_t)t * RS + 64 * half + c0);
    }
  };
  auto writeK = [&](const float4 (&s)[8], unsigned short* bb) {
#pragma unroll
    for (int it = 0; it < 8; ++it) {
      const int f = it * 256 + tid;
      const int t = f >> 4;
      const int c0 = (f & 15) << 2;
      ushort4 ku;
      ku.x = f2bf(s[it].x); ku.y = f2bf(s[it].y);
      ku.z = f2bf(s[it].z); ku.w = f2bf(s[it].w);
      *(ushort4*)&bb[sw64(t, c0)] = ku;
    }
  };
  auto loadV = [&](int half, float4 (&s)[8]) {
#pragma unroll
    for (int it = 0; it < 8; ++it) {
      const int sl = (tid & 15) | ((it & 3) << 4);
      const int c0 = ((tid >> 4) | ((it >> 2) << 4)) << 2;
      const int sd = 64 * half + sl;
      s[it] = *(const float4*)(vg + cbase + (size_t)sd * RS + c0);
    }
  };
  auto writeV = [&](const float4 (&s)[8], unsigned short* bb) {
#pragma unroll
    for (int it = 0; it < 8; ++it) {
      const int sl = (tid & 15) | ((it & 3) << 4);
      const int c0 = ((tid >> 4) | ((it >> 2) << 4)) << 2;
      bb[sw64(c0 + 0, sl)] = f2bf(s[it].x);
      bb[sw64(c0 + 1, sl)] = f2bf(s[it].y);
      bb[sw64(c0 + 2, sl)] = f2bf(s[it].z);
      bb[sw64(c0 + 3, sl)] = f2bf(s[it].w);
    }
  };
  auto loadH = [&](int half, uint4 (&hr)[2][4]) {
#pragma unroll
    for (int m = 0; m < 2; ++m) {
      if (m >= nmat) break;
      const int slot = (m < sseg) ? 0 : n;
#pragma unroll
      for (int it = 0; it < 4; ++it) {
        const int f = it * 256 + tid;
        const int dv = f >> 3;
        const int c8 = (f & 7) << 3;
        hr[m][it] = *(const uint4*)(st + sbh + ((size_t)slot << 14) +
                                    (size_t)dv * 128 + 64 * half + c8);
      }
    }
  };
  auto writeH = [&](const uint4 (&hr)[2][4], unsigned short* bb) {
#pragma unroll
    for (int it = 0; it < 4; ++it) {
      const int f = it * 256 + tid;
      const int dv = f >> 3;
      const int c8 = (f & 7) << 3;
      uint4 out;
      if (nmat == 1) {
        out = hr[0][it];
      } else {
        const unsigned a[4] = {hr[0][it].x, hr[0][it].y, hr[0][it].z, hr[0][it].w};
        const unsigned c[4] = {hr[1][it].x, hr[1][it].y, hr[1][it].z, hr[1][it].w};
        unsigned pk[4];
#pragma unroll
        for (int e = 0; e < 4; ++e) {
          const float lo = bf2f((unsigned short)(a[e] & 0xFFFFu)) +
                           bf2f((unsigned short)(c[e] & 0xFFFFu));
          const float hi = bf2f((unsigned short)(a[e] >> 16)) +
                           bf2f((unsigned short)(c[e] >> 16));
          pk[e] = (unsigned)f2bf(lo) | ((unsigned)f2bf(hi) << 16);
        }
        out.x = pk[0]; out.y = pk[1]; out.z = pk[2]; out.w = pk[3];
      }
      *(uint4*)&bb[sw64(dv, c8)] = out;
    }
  };

  // ---- compute lambdas ----
  auto gemmO = [&](const unsigned short* bb, int half) {
#pragma unroll
    for (int kt = 0; kt < 2; ++kt) {
      const int ktg = 2 * half + kt;
      frag_ab af[2], bf_[4];
#pragma unroll
      for (int mt = 0; mt < 2; ++mt)
        af[mt] = *(const frag_ab*)&QP[sw128(32 * wr + 16 * mt + li, 32 * ktg + 8 * q4)];
#pragma unroll
      for (int nt = 0; nt < 4; ++nt)
        bf_[nt] = *(const frag_ab*)&bb[sw64(64 * wc + 16 * nt + li, 32 * kt + 8 * q4)];
#pragma unroll
      for (int mt = 0; mt < 2; ++mt)
#pragma unroll
        for (int nt = 0; nt < 4; ++nt)
          accO[mt][nt] = __builtin_amdgcn_mfma_f32_16x16x32_bf16(af[mt], bf_[nt], accO[mt][nt], 0, 0, 0);
    }
  };
  auto gemmP = [&](const unsigned short* bb, int half) {
    if (64 * wc <= 64 * tb + 32 * wr + 31) {
#pragma unroll
      for (int kt = 0; kt < 2; ++kt) {
        const int ktg = 2 * half + kt;
        frag_ab af[2], bf_[4];
#pragma unroll
        for (int mt = 0; mt < 2; ++mt)
          af[mt] = *(const frag_ab*)&QP[sw128(32 * wr + 16 * mt + li, 32 * ktg + 8 * q4)];
#pragma unroll
        for (int nt = 0; nt < 4; ++nt)
          bf_[nt] = *(const frag_ab*)&bb[sw64(64 * wc + 16 * nt + li, 32 * kt + 8 * q4)];
#pragma unroll
        for (int mt = 0; mt < 2; ++mt)
#pragma unroll
          for (int nt = 0; nt < 4; ++nt)
            if (64 * wc + 16 * nt <= 64 * tb + 32 * wr + 16 * mt + 15)
              accP[mt][nt] = __builtin_amdgcn_mfma_f32_16x16x32_bf16(af[mt], bf_[nt], accP[mt][nt], 0, 0, 0);
      }
    }
  };
  auto gemmV = [&](const unsigned short* bb, int half) {
#pragma unroll
    for (int kt = 0; kt < 2; ++kt) {
      const int ktg = 2 * half + kt;
      if (32 * ktg > 64 * tb + 32 * wr + 31) continue;
      frag_ab af[2], bf_[4];
#pragma unroll
      for (int mt = 0; mt < 2; ++mt)
        af[mt] = *(const frag_ab*)&QP[sw128(32 * wr + 16 * mt + li, 32 * ktg + 8 * q4)];
#pragma unroll
      for (int nt = 0; nt < 4; ++nt)
        bf_[nt] = *(const frag_ab*)&bb[sw64(64 * wc + 16 * nt + li, 32 * kt + 8 * q4)];
#pragma unroll
      for (int mt = 0; mt < 2; ++mt)
#pragma unroll
        for (int nt = 0; nt < 4; ++nt)
          if (32 * ktg <= 64 * tb + 32 * wr + 16 * mt + 15)
            accO[mt][nt] = __builtin_amdgcn_mfma_f32_16x16x32_bf16(af[mt], bf_[nt], accO[mt][nt], 0, 0, 0);
    }
  };
  auto pwrite = [&]() {
#pragma unroll
    for (int mt = 0; mt < 2; ++mt)
#pragma unroll
      for (int nt = 0; nt < 4; ++nt) {
        const int t0 = 32 * wr + 16 * mt + 4 * q4;
        const int s = 64 * wc + 16 * nt + li;
#pragma unroll
        for (int r = 0; r < 4; ++r) {
          const int t = t0 + r;
          QP[sw128(t, s)] = (s <= t + 64 * tb) ? f2bf(accP[mt][nt][r]) : (unsigned short)0;
        }
      }
  };

  // ---- prologue: Q -> QP; K0 -> buf0; issue K1 ----
  {
    float4 qr[8];
#pragma unroll
    for (int it = 0; it < 8; ++it) {
      const int f = it * 256 + tid;
      const int t = f >> 5;
      const int c0 = (f & 31) << 2;
      qr[it] = *(const float4*)(qg + tbase + (size_t)t * RS + c0);
    }
    loadK(0, sA);
#pragma unroll
    for (int it = 0; it < 8; ++it) {
      const int f = it * 256 + tid;
      const int t = f >> 5;
      const int c0 = (f & 31) << 2;
      ushort4 qu;
      qu.x = f2bf(qr[it].x * SCALE); qu.y = f2bf(qr[it].y * SCALE);
      qu.z = f2bf(qr[it].z * SCALE); qu.w = f2bf(qr[it].w * SCALE);
      *(ushort4*)&QP[sw128(t, c0)] = qu;
    }
    loadK(1, sB);
    writeK(sA, Bb[0]);
  }
  __syncthreads();

  if (nmat) {
    // S0: QK dk-half0 (buf0); stage K1 -> buf1; issue H0
    loadH(0, hA);
    writeK(sB, Bb[1]);
    gemmP(Bb[0], 0);
    __syncthreads();
    // S1: QK dk-half1 (buf1); stage H0 -> buf0; issue H1
    loadH(1, hB);
    writeH(hA, Bb[0]);
    gemmP(Bb[1], 1);
    __syncthreads();
    // S2: H-GEMM dk-half0 (buf0); stage H1 -> buf1; issue V0
    loadV(0, sA);
    writeH(hB, Bb[1]);
    gemmO(Bb[0], 0);
    __syncthreads();
    // S3: H-GEMM dk-half1 (buf1); stage V0 -> buf0; issue V1 (tb=1)
    if (tb) loadV(1, sB);
    writeV(sA, Bb[0]);
    gemmO(Bb[1], 1);
    __syncthreads();
    // SP: all QP (Q) reads done -> overwrite with P
    pwrite();
    __syncthreads();
    // S4: PV s-half0 (buf0); stage V1 -> buf1 (tb=1)
    if (tb) writeV(sB, Bb[1]);
    gemmV(Bb[0], 0);
    if (tb) {
      __syncthreads();
      // S5: PV s-half1 (buf1)
      gemmV(Bb[1], 1);
    }
  } else {
    // nmat==0 (n==0): no H-GEMM.
    // S0: QK dk-half0 (buf0); stage K1 -> buf1; issue V0
    loadV(0, sA);
    writeK(sB, Bb[1]);
    gemmP(Bb[0], 0);
    __syncthreads();
    // S1: QK dk-half1 (buf1); stage V0 -> buf0; issue V1 (tb=1)
    if (tb) loadV(1, sB);
    writeV(sA, Bb[0]);
    gemmP(Bb[1], 1);
    __syncthreads();
    pwrite();
    __syncthreads();
    // S2: PV s-half0 (buf0); stage V1 -> buf1 (tb=1)
    if (tb) writeV(sB, Bb[1]);
    gemmV(Bb[0], 0);
    if (tb) {
      __syncthreads();
      gemmV(Bb[1], 1);
    }
  }

  // store O fp32 (single write, no RMW)
#pragma unroll
  for (int mt = 0; mt < 2; ++mt)
#pragma unroll
    for (int nt = 0; nt < 4; ++nt)
#pragma unroll
      for (int r = 0; r < 4; ++r) {
        const int t = 32 * wr + 16 * mt + 4 * q4 + r;
        const int dv = 64 * wc + 16 * nt + li;
        o[tbase + (size_t)t * RS + dv] = accO[mt][nt][r];
      }
}

extern "C" void kernel_launch(void* const* d_in, const int* in_sizes, int n_in,
                              void* d_out, int out_size, void* d_ws, size_t ws_size,
                              hipStream_t stream) {
  const float* q = (const float*)d_in[0];
  const float* k = (const float*)d_in[1];
  const float* v = (const float*)d_in[2];
  float* o = (float*)d_out;
  unsigned short* st = (unsigned short*)d_ws;  // 32 MiB
  hipLaunchKernelGGL(phA_state, dim3(BHt * 8 * NSEG), dim3(256), 0, stream, k, v, st);
  hipLaunchKernelGGL(phB_out, dim3(BHt * NCH * 2), dim3(256), 0, stream, q, k, v, st, o);
}

// Round 5
// 274.996 us; speedup vs baseline: 1.1641x; 1.1641x over previous
//
#include <hip/hip_runtime.h>

// Chunked linear attention (causal, unnormalized), bf16 MFMA, fp32 I/O.
// R8: R7 pipeline, spill fix — phB __launch_bounds__(256) (no min-waves cap;
//     R7's (256,3) capped VGPRs ~170 and spilled the staging arrays:
//     WRITE_SIZE 68->163 MB was scratch, not O).
//   phA: split-scan, grid bh x slice x seg (64*8*2=1024), CPS=8, NSEG=2.
//   phB: block=(bh,n,tb). Stage order K0,K1,[H0,H1],P,V0,[V1] with Bb[2]
//        ping-pong; global->reg issue at stage i-1, reg->LDS at stage i,
//        consume at stage i+1. One barrier per stage.
// B=4 S=2048 H=16 D=128. ws: 64*16*128*128 bf16 = 32 MiB.

#define Bc 4
#define Sq 2048
#define Hh 16
#define Dd 128
#define RS (Hh * Dd)      // 2048
#define Cc 128
#define NCH (Sq / Cc)     // 16
#define BHt (Bc * Hh)     // 64
#define NSEG 2
#define CPS (NCH / NSEG)  // 8
#define SCALE 0.08838834764831845f

using frag_ab = __attribute__((ext_vector_type(8))) short;  // 8 bf16
using frag_cd = __attribute__((ext_vector_type(4))) float;  // 4 fp32

__device__ __forceinline__ unsigned short f2bf(float f) {
  union { float f; unsigned u; } x; x.f = f;
  unsigned r = x.u + 0x7FFFu + ((x.u >> 16) & 1u);  // RNE
  return (unsigned short)(r >> 16);
}
__device__ __forceinline__ float bf2f(unsigned short u) {
  union { unsigned u; float f; } x; x.u = ((unsigned)u) << 16;
  return x.f;
}
// swizzles: permute 8-element (16 B) blocks within a row -> frag b128 reads
// stay contiguous; writes spread across banks.
__device__ __forceinline__ int sw64(int r, int c) {
  return r * 64 + ((((c >> 3) ^ (r & 7)) << 3) | (c & 7));
}
__device__ __forceinline__ int sw128(int r, int c) {
  return r * 128 + ((((c >> 3) ^ (r & 15)) << 3) | (c & 7));
}
__device__ __forceinline__ int swKT(int dk, int t) {  // [dk 128][t 128]
  return dk * 128 + ((((t >> 3) ^ (dk ^ (dk >> 4))) & 15) << 3) + (t & 7);
}
__device__ __forceinline__ int swVT(int dv, int t) {  // [dv 16][t 128]
  return dv * 128 + ((((t >> 3) ^ dv) & 15) << 3) + (t & 7);
}

// ---------- phA: split scan. Block = (bh, slice, seg); scans CPS chunks ----
// bid layout: bh low 6 bits (XCD-colocate), slice bits 6-8, seg bit 9.
__global__ __launch_bounds__(256) void phA_state(const float* __restrict__ kg,
                                                 const float* __restrict__ vg,
                                                 unsigned short* __restrict__ st) {
  __shared__ unsigned short KT[128 * 128];  // 32 KB [dk][t]
  __shared__ unsigned short VT[16 * 128];   //  4 KB [dv][t]
  const int tid = threadIdx.x;
  const int bh = blockIdx.x & 63;
  const int slice = (blockIdx.x >> 6) & 7;
  const int seg = blockIdx.x >> 9;
  const int b = bh >> 4, h = bh & 15;
  const int dv0 = slice * 16;
  const size_t base = (size_t)b * Sq * RS + (size_t)h * Dd;
  const int w = tid >> 6, L = tid & 63, li = L & 15, q4 = L >> 4;
  const int kdk0 = (tid & 31) * 4;
  const int ktg4 = (tid >> 5) * 4;
  const int vdv0l = (tid & 3) * 4;
  const int vt0 = (tid >> 2) * 2;

  float4 rk[4][4];
  float4 rv[2];
  auto prefetch = [&](int n) {
    const size_t t0g = (size_t)n * Cc;
#pragma unroll
    for (int p = 0; p < 4; ++p) {
      const int t0 = p * 32 + ktg4;
#pragma unroll
      for (int i = 0; i < 4; ++i)
        rk[p][i] = *(const float4*)(kg + base + (t0g + t0 + i) * (size_t)RS + kdk0);
    }
#pragma unroll
    for (int i = 0; i < 2; ++i)
      rv[i] = *(const float4*)(vg + base + (t0g + vt0 + i) * (size_t)RS + dv0 + vdv0l);
  };

  frag_cd acc[2];
  acc[0] = (frag_cd){0.f, 0.f, 0.f, 0.f};
  acc[1] = (frag_cd){0.f, 0.f, 0.f, 0.f};
  const int n0 = seg * CPS;
  prefetch(n0);
  const size_t sbb = (size_t)bh * NCH * (128 * 128);

  auto store_acc = [&](int slot) {
    const size_t sb = sbb + (size_t)slot * (128 * 128);
#pragma unroll
    for (int nt = 0; nt < 2; ++nt)
#pragma unroll
      for (int r = 0; r < 4; ++r) {
        const int dv = dv0 + 4 * q4 + r;
        const int dk = 32 * w + 16 * nt + li;
        st[sb + (size_t)dv * 128 + dk] = f2bf(acc[nt][r]);
      }
  };

  for (int j = 0; j < CPS; ++j) {
    __syncthreads();  // prev chunk's frag reads done
#pragma unroll
    for (int p = 0; p < 4; ++p) {
      const int t0 = p * 32 + ktg4;
#pragma unroll
      for (int jj = 0; jj < 4; ++jj) {
        ushort4 u;
        u.x = f2bf(((const float*)&rk[p][0])[jj]);
        u.y = f2bf(((const float*)&rk[p][1])[jj]);
        u.z = f2bf(((const float*)&rk[p][2])[jj]);
        u.w = f2bf(((const float*)&rk[p][3])[jj]);
        *(ushort4*)&KT[swKT(kdk0 + jj, t0)] = u;
      }
    }
#pragma unroll
    for (int jj = 0; jj < 4; ++jj) {
      ushort2 u;
      u.x = f2bf(((const float*)&rv[0])[jj]);
      u.y = f2bf(((const float*)&rv[1])[jj]);
      *(ushort2*)&VT[swVT(vdv0l + jj, vt0)] = u;
    }
    if (j + 1 < CPS) prefetch(n0 + j + 1);  // HBM latency hides under LDS+MFMA
    __syncthreads();
    if (j > 0) store_acc(n0 + j);  // local EXCLUSIVE prefix
#pragma unroll
    for (int kt = 0; kt < 4; ++kt) {
      frag_ab af = *(const frag_ab*)&VT[swVT(li, 32 * kt + 8 * q4)];
#pragma unroll
      for (int nt = 0; nt < 2; ++nt) {
        frag_ab bf = *(const frag_ab*)&KT[swKT(32 * w + 16 * nt + li, 32 * kt + 8 * q4)];
        acc[nt] = __builtin_amdgcn_mfma_f32_16x16x32_bf16(af, bf, acc[nt], 0, 0, 0);
      }
    }
  }
  if (seg + 1 < NSEG) store_acc(n0);  // segment total T_0 -> slot 0
}

// ---------- phB: O = Qs*H_n + tril(Qs*K^T)*V, 64 query rows per block ----
// H_n = T_0 (slot 0, if n>=8) + local (slot n, if n&7). Pipelined stages.
// NOTE: no min-waves in launch_bounds — the staging arrays need ~180-210
// VGPRs; capping at (256,3) spilled to scratch (R7: +100 MB WRITE_SIZE).
__global__ __launch_bounds__(256) void phB_out(const float* __restrict__ qg,
                                               const float* __restrict__ kg,
                                               const float* __restrict__ vg,
                                               const unsigned short* __restrict__ st,
                                               float* __restrict__ o) {
  __shared__ unsigned short QP[64 * 128];     // 16 KB: Qs rows of this tb, later P
  __shared__ unsigned short Bb[2][128 * 64];  // 2 x 16 KB ping-pong stages
  const int tid = threadIdx.x;
  const int bid = blockIdx.x;
  const int bh = bid & 63, n = (bid >> 6) & 15, tb = bid >> 10;
  const int b = bh >> 4, h = bh & 15;
  const size_t cbase = (size_t)b * Sq * RS + (size_t)n * Cc * RS + (size_t)h * Dd;
  const size_t tbase = cbase + (size_t)(64 * tb) * RS;
  const size_t sbh = (size_t)bh * NCH * (128 * 128);
  const int sseg = n >> 3, jj = n & 7;
  const int nmat = sseg + (jj ? 1 : 0);  // 0..2
  const int w = tid >> 6, L = tid & 63;
  const int wr = w >> 1, wc = w & 1, li = L & 15, q4 = L >> 4;

  frag_cd accO[2][4], accP[2][4];
#pragma unroll
  for (int i = 0; i < 2; ++i)
#pragma unroll
    for (int j = 0; j < 4; ++j) {
      accO[i][j] = (frag_cd){0.f, 0.f, 0.f, 0.f};
      accP[i][j] = (frag_cd){0.f, 0.f, 0.f, 0.f};
    }

  float4 sA[8], sB[8];       // K/V staging regs
  uint4 hA[2][4], hB[2][4];  // H carry staging regs (nmat<=2)

  // ---- staging lambdas (load = issue global->reg; write = reg->LDS) ----
  auto loadK = [&](int half, float4 (&s)[8]) {
#pragma unroll
    for (int it = 0; it < 8; ++it) {
      const int f = it * 256 + tid;
      const int t = f >> 4;
      const int c0 = (f & 15) << 2;
      s[it] = *(const float4*)(kg + cbase + (size_t)t * RS + 64 * half + c0);
    }
  };
  auto writeK = [&](const float4 (&s)[8], unsigned short* bb) {
#pragma unroll
    for (int it = 0; it < 8; ++it) {
      const int f = it * 256 + tid;
      const int t = f >> 4;
      const int c0 = (f & 15) << 2;
      ushort4 ku;
      ku.x = f2bf(s[it].x); ku.y = f2bf(s[it].y);
      ku.z = f2bf(s[it].z); ku.w = f2bf(s[it].w);
      *(ushort4*)&bb[sw64(t, c0)] = ku;
    }
  };
  auto loadV = [&](int half, float4 (&s)[8]) {
#pragma unroll
    for (int it = 0; it < 8; ++it) {
      const int sl = (tid & 15) | ((it & 3) << 4);
      const int c0 = ((tid >> 4) | ((it >> 2) << 4)) << 2;
      const int sd = 64 * half + sl;
      s[it] = *(const float4*)(vg + cbase + (size_t)sd * RS + c0);
    }
  };
  auto writeV = [&](const float4 (&s)[8], unsigned short* bb) {
#pragma unroll
    for (int it = 0; it < 8; ++it) {
      const int sl = (tid & 15) | ((it & 3) << 4);
      const int c0 = ((tid >> 4) | ((it >> 2) << 4)) << 2;
      bb[sw64(c0 + 0, sl)] = f2bf(s[it].x);
      bb[sw64(c0 + 1, sl)] = f2bf(s[it].y);
      bb[sw64(c0 + 2, sl)] = f2bf(s[it].z);
      bb[sw64(c0 + 3, sl)] = f2bf(s[it].w);
    }
  };
  auto loadH = [&](int half, uint4 (&hr)[2][4]) {
#pragma unroll
    for (int m = 0; m < 2; ++m) {
      if (m >= nmat) break;
      const int slot = (m < sseg) ? 0 : n;
#pragma unroll
      for (int it = 0; it < 4; ++it) {
        const int f = it * 256 + tid;
        const int dv = f >> 3;
        const int c8 = (f & 7) << 3;
        hr[m][it] = *(const uint4*)(st + sbh + ((size_t)slot << 14) +
                                    (size_t)dv * 128 + 64 * half + c8);
      }
    }
  };
  auto writeH = [&](const uint4 (&hr)[2][4], unsigned short* bb) {
#pragma unroll
    for (int it = 0; it < 4; ++it) {
      const int f = it * 256 + tid;
      const int dv = f >> 3;
      const int c8 = (f & 7) << 3;
      uint4 out;
      if (nmat == 1) {
        out = hr[0][it];
      } else {
        const unsigned a[4] = {hr[0][it].x, hr[0][it].y, hr[0][it].z, hr[0][it].w};
        const unsigned c[4] = {hr[1][it].x, hr[1][it].y, hr[1][it].z, hr[1][it].w};
        unsigned pk[4];
#pragma unroll
        for (int e = 0; e < 4; ++e) {
          const float lo = bf2f((unsigned short)(a[e] & 0xFFFFu)) +
                           bf2f((unsigned short)(c[e] & 0xFFFFu));
          const float hi = bf2f((unsigned short)(a[e] >> 16)) +
                           bf2f((unsigned short)(c[e] >> 16));
          pk[e] = (unsigned)f2bf(lo) | ((unsigned)f2bf(hi) << 16);
        }
        out.x = pk[0]; out.y = pk[1]; out.z = pk[2]; out.w = pk[3];
      }
      *(uint4*)&bb[sw64(dv, c8)] = out;
    }
  };

  // ---- compute lambdas ----
  auto gemmO = [&](const unsigned short* bb, int half) {
#pragma unroll
    for (int kt = 0; kt < 2; ++kt) {
      const int ktg = 2 * half + kt;
      frag_ab af[2], bf_[4];
#pragma unroll
      for (int mt = 0; mt < 2; ++mt)
        af[mt] = *(const frag_ab*)&QP[sw128(32 * wr + 16 * mt + li, 32 * ktg + 8 * q4)];
#pragma unroll
      for (int nt = 0; nt < 4; ++nt)
        bf_[nt] = *(const frag_ab*)&bb[sw64(64 * wc + 16 * nt + li, 32 * kt + 8 * q4)];
#pragma unroll
      for (int mt = 0; mt < 2; ++mt)
#pragma unroll
        for (int nt = 0; nt < 4; ++nt)
          accO[mt][nt] = __builtin_amdgcn_mfma_f32_16x16x32_bf16(af[mt], bf_[nt], accO[mt][nt], 0, 0, 0);
    }
  };
  auto gemmP = [&](const unsigned short* bb, int half) {
    if (64 * wc <= 64 * tb + 32 * wr + 31) {
#pragma unroll
      for (int kt = 0; kt < 2; ++kt) {
        const int ktg = 2 * half + kt;
        frag_ab af[2], bf_[4];
#pragma unroll
        for (int mt = 0; mt < 2; ++mt)
          af[mt] = *(const frag_ab*)&QP[sw128(32 * wr + 16 * mt + li, 32 * ktg + 8 * q4)];
#pragma unroll
        for (int nt = 0; nt < 4; ++nt)
          bf_[nt] = *(const frag_ab*)&bb[sw64(64 * wc + 16 * nt + li, 32 * kt + 8 * q4)];
#pragma unroll
        for (int mt = 0; mt < 2; ++mt)
#pragma unroll
          for (int nt = 0; nt < 4; ++nt)
            if (64 * wc + 16 * nt <= 64 * tb + 32 * wr + 16 * mt + 15)
              accP[mt][nt] = __builtin_amdgcn_mfma_f32_16x16x32_bf16(af[mt], bf_[nt], accP[mt][nt], 0, 0, 0);
      }
    }
  };
  auto gemmV = [&](const unsigned short* bb, int half) {
#pragma unroll
    for (int kt = 0; kt < 2; ++kt) {
      const int ktg = 2 * half + kt;
      if (32 * ktg > 64 * tb + 32 * wr + 31) continue;
      frag_ab af[2], bf_[4];
#pragma unroll
      for (int mt = 0; mt < 2; ++mt)
        af[mt] = *(const frag_ab*)&QP[sw128(32 * wr + 16 * mt + li, 32 * ktg + 8 * q4)];
#pragma unroll
      for (int nt = 0; nt < 4; ++nt)
        bf_[nt] = *(const frag_ab*)&bb[sw64(64 * wc + 16 * nt + li, 32 * kt + 8 * q4)];
#pragma unroll
      for (int mt = 0; mt < 2; ++mt)
#pragma unroll
        for (int nt = 0; nt < 4; ++nt)
          if (32 * ktg <= 64 * tb + 32 * wr + 16 * mt + 15)
            accO[mt][nt] = __builtin_amdgcn_mfma_f32_16x16x32_bf16(af[mt], bf_[nt], accO[mt][nt], 0, 0, 0);
    }
  };
  auto pwrite = [&]() {
#pragma unroll
    for (int mt = 0; mt < 2; ++mt)
#pragma unroll
      for (int nt = 0; nt < 4; ++nt) {
        const int t0 = 32 * wr + 16 * mt + 4 * q4;
        const int s = 64 * wc + 16 * nt + li;
#pragma unroll
        for (int r = 0; r < 4; ++r) {
          const int t = t0 + r;
          QP[sw128(t, s)] = (s <= t + 64 * tb) ? f2bf(accP[mt][nt][r]) : (unsigned short)0;
        }
      }
  };

  // ---- prologue: Q -> QP; K0 -> buf0; issue K1 ----
  {
    float4 qr[8];
#pragma unroll
    for (int it = 0; it < 8; ++it) {
      const int f = it * 256 + tid;
      const int t = f >> 5;
      const int c0 = (f & 31) << 2;
      qr[it] = *(const float4*)(qg + tbase + (size_t)t * RS + c0);
    }
    loadK(0, sA);
#pragma unroll
    for (int it = 0; it < 8; ++it) {
      const int f = it * 256 + tid;
      const int t = f >> 5;
      const int c0 = (f & 31) << 2;
      ushort4 qu;
      qu.x = f2bf(qr[it].x * SCALE); qu.y = f2bf(qr[it].y * SCALE);
      qu.z = f2bf(qr[it].z * SCALE); qu.w = f2bf(qr[it].w * SCALE);
      *(ushort4*)&QP[sw128(t, c0)] = qu;
    }
    loadK(1, sB);
    writeK(sA, Bb[0]);
  }
  __syncthreads();

  if (nmat) {
    // S0: QK dk-half0 (buf0); stage K1 -> buf1; issue H0
    loadH(0, hA);
    writeK(sB, Bb[1]);
    gemmP(Bb[0], 0);
    __syncthreads();
    // S1: QK dk-half1 (buf1); stage H0 -> buf0; issue H1
    loadH(1, hB);
    writeH(hA, Bb[0]);
    gemmP(Bb[1], 1);
    __syncthreads();
    // S2: H-GEMM dk-half0 (buf0); stage H1 -> buf1; issue V0
    loadV(0, sA);
    writeH(hB, Bb[1]);
    gemmO(Bb[0], 0);
    __syncthreads();
    // S3: H-GEMM dk-half1 (buf1); stage V0 -> buf0; issue V1 (tb=1)
    if (tb) loadV(1, sB);
    writeV(sA, Bb[0]);
    gemmO(Bb[1], 1);
    __syncthreads();
    // SP: all QP (Q) reads done -> overwrite with P
    pwrite();
    __syncthreads();
    // S4: PV s-half0 (buf0); stage V1 -> buf1 (tb=1)
    if (tb) writeV(sB, Bb[1]);
    gemmV(Bb[0], 0);
    if (tb) {
      __syncthreads();
      // S5: PV s-half1 (buf1)
      gemmV(Bb[1], 1);
    }
  } else {
    // nmat==0 (n==0): no H-GEMM.
    // S0: QK dk-half0 (buf0); stage K1 -> buf1; issue V0
    loadV(0, sA);
    writeK(sB, Bb[1]);
    gemmP(Bb[0], 0);
    __syncthreads();
    // S1: QK dk-half1 (buf1); stage V0 -> buf0; issue V1 (tb=1)
    if (tb) loadV(1, sB);
    writeV(sA, Bb[0]);
    gemmP(Bb[1], 1);
    __syncthreads();
    pwrite();
    __syncthreads();
    // S2: PV s-half0 (buf0); stage V1 -> buf1 (tb=1)
    if (tb) writeV(sB, Bb[1]);
    gemmV(Bb[0], 0);
    if (tb) {
      __syncthreads();
      gemmV(Bb[1], 1);
    }
  }

  // store O fp32 (single write, no RMW)
#pragma unroll
  for (int mt = 0; mt < 2; ++mt)
#pragma unroll
    for (int nt = 0; nt < 4; ++nt)
#pragma unroll
      for (int r = 0; r < 4; ++r) {
        const int t = 32 * wr + 16 * mt + 4 * q4 + r;
        const int dv = 64 * wc + 16 * nt + li;
        o[tbase + (size_t)t * RS + dv] = accO[mt][nt][r];
      }
}

extern "C" void kernel_launch(void* const* d_in, const int* in_sizes, int n_in,
                              void* d_out, int out_size, void* d_ws, size_t ws_size,
                              hipStream_t stream) {
  const float* q = (const float*)d_in[0];
  const float* k = (const float*)d_in[1];
  const float* v = (const float*)d_in[2];
  float* o = (float*)d_out;
  unsigned short* st = (unsigned short*)d_ws;  // 32 MiB
  hipLaunchKernelGGL(phA_state, dim3(BHt * 8 * NSEG), dim3(256), 0, stream, k, v, st);
  hipLaunchKernelGGL(phB_out, dim3(BHt * NCH * 2), dim3(256), 0, stream, q, k, v, st, o);
}